// Round 8
// baseline (92.075 us; speedup 1.0000x reference)
//
#include <hip/hip_runtime.h>

#define NGRID 257
#define BLOCK 1024
#define GRID 256
#define OUTER 8        // 2 points/iter: 256*1024*16 == 4,194,304 exactly

// ---------------- LDS layout (163,604 B of 163,840) ----------------
// MAIN: rows 0..255 x cols 0..255, f16, pitch 256 halves (512 B). b64 row reads
//       at byte 512*r + 8*i1: pair-slot = i1 mod 16 (uniform-16, random floor --
//       permutation cannot reduce E[max-bin] of a uniform slot distribution).
// S1  : row 256, cols 0..255 (512 B) -- j=4 b64 when i0==63 (branchless cndmask).
// T   : transposed 5th-columns, dword-packed: T[c1] = col (4*c1+4), row-pairs
//       (2d, 2d+1), d = 0..124. Stride 125 dwords == 29 (mod 32), gcd(29,32)=1
//       -> b32 slot = (29*c1 + 2*i0 + k) uniform over ALL 32 banks. Replaces the
//       5 even-bank-only b32 gathers with 3 full-spread b32s.
// S2  : col 256, rows 248..256 (9 halves) -- (i1==63, i0>=62) fallback.
#define OFF1_H  65536              // S1 at byte 131072
#define T_DW    32896              // T  at byte 131584 (dword index)
#define S2_H    81792              // S2 at byte 163584
#define LDS_BYTES 163616

typedef _Float16 half2_t __attribute__((ext_vector_type(2)));
typedef _Float16 half4_t __attribute__((ext_vector_type(4)));
typedef float    f32x2  __attribute__((ext_vector_type(2)));

struct __attribute__((packed, aligned(4))) f4u { float x, y, z, w; };

__device__ __forceinline__ half2_t pack2(float a, float b) {
    return __builtin_bit_cast(half2_t, __builtin_amdgcn_cvt_pkrtz(a, b));
}

// Lagrange denominator reciprocal for grid index r (mod 4); folded at staging.
__device__ __forceinline__ float rowscale(int r) {
    return (r & 1) ? (-1.0f / 6.0f) : ((r & 2) ? 0.25f : (1.0f / 24.0f));
}

// Packed numerator basis for both dims of one point (denoms folded into LDS coe).
__device__ __forceinline__ void nbasis(f32x2 fr, f32x2 n[5]) {
    f32x2 f0 = fr * 4.0f;
    f32x2 f1 = f0 - 1.0f;
    f32x2 f2 = f0 - 2.0f;
    f32x2 f3 = f1 - 2.0f;
    f32x2 f4 = f0 - 4.0f;
    f32x2 p01 = f0 * f1;
    f32x2 p12 = f1 * f2;
    f32x2 p23 = f2 * f3;
    f32x2 p34 = f3 * f4;
    n[0] = p12 * p34;
    n[1] = (f0 * f2) * p34;
    n[2] = p01 * p34;
    n[3] = p01 * (f2 * f4);
    n[4] = p01 * p23;
}

// One point: 5 b64 row reads (main/S1) + 3 full-bank-spread b32 T reads.
// Rare lanes (i0 >= 62: 3.1%) divergently re-fetch the 5th column (execz-skipped
// in the common case).
__device__ __forceinline__ float eval_pt(const _Float16* __restrict__ lds,
                                         float x0, float x1) {
    float u0 = x0 * 64.0f, u1 = x1 * 64.0f;
    int i0 = (int)u0;
    int i1 = (int)u1;
    f32x2 fr = { __builtin_amdgcn_fractf(u0), __builtin_amdgcn_fractf(u1) };

    // ---- issue all gathers up front ----
    const _Float16* mb = lds + (i0 << 10) + (i1 << 2);   // row 4*i0, cols 4*i1..
    half4_t l0 = *(const half4_t*)(mb);
    half4_t l1 = *(const half4_t*)(mb + 256);
    half4_t l2 = *(const half4_t*)(mb + 512);
    half4_t l3 = *(const half4_t*)(mb + 768);
    const _Float16* p4 = (i0 < 63) ? (mb + 1024) : (lds + OFF1_H + (i1 << 2));
    half4_t l4 = *(const half4_t*)(p4);

    // T reads: unconditional (i0 >= 62 reads in-bounds junk, overwritten below)
    const unsigned* tp = (const unsigned*)lds + T_DW + 125 * i1 + 2 * i0;
    unsigned D0 = tp[0], D1 = tp[1], D2 = tp[2];

    // ---- bases (VALU overlaps DS latency) ----
    f32x2 n[5];
    nbasis(fr, n);
    half2_t q01 = pack2(n[0][1], n[1][1]);   // col weights (dim 1) for b64 dots
    half2_t q23 = pack2(n[2][1], n[3][1]);
    half2_t pA  = pack2(n[0][0], n[1][0]);   // row weights (dim 0) for T dot
    half2_t pB  = pack2(n[2][0], n[3][0]);

    half2_t C01 = __builtin_bit_cast(half2_t, D0);
    half2_t C23 = __builtin_bit_cast(half2_t, D1);
    _Float16 C4 = __builtin_bit_cast(half2_t, D2)[0];
    if (__builtin_expect(i0 >= 62, 0)) {     // rows 248..256 not in T
        _Float16 v[5];
#pragma unroll
        for (int i = 0; i < 5; ++i) {
            int r = 4 * i0 + i;
            const _Float16* p;
            if (i1 < 63) p = (r < 256) ? (lds + (r << 8) + (i1 << 2) + 4)
                                       : (lds + OFF1_H + (i1 << 2) + 4);
            else         p = lds + S2_H + (r - 248);
            v[i] = *p;
        }
        C01 = half2_t{ v[0], v[1] };
        C23 = half2_t{ v[2], v[3] };
        C4  = v[4];
    }

    // ---- 5th-column dot (row weights), then 4-col dots (col weights) ----
    float cs = (float)C4 * n[4][0];
    cs = __builtin_amdgcn_fdot2(C23, pB, cs, false);
    cs = __builtin_amdgcn_fdot2(C01, pA, cs, false);

    half4_t lo[5] = { l0, l1, l2, l3, l4 };
    float rd[5];
#pragma unroll
    for (int i = 0; i < 5; ++i) {
        half2_t xy = __builtin_shufflevector(lo[i], lo[i], 0, 1);
        half2_t zw = __builtin_shufflevector(lo[i], lo[i], 2, 3);
        rd[i] = __builtin_amdgcn_fdot2(xy, q01,
                __builtin_amdgcn_fdot2(zw, q23, 0.0f, false), false);
    }
    // dual-chain accumulation
    float accA = n[4][0] * rd[4];
    accA = fmaf(n[0][0], rd[0], accA);
    accA = fmaf(n[2][0], rd[2], accA);
    float accB = n[4][1] * cs;               // 5th-column contribution
    accB = fmaf(n[1][0], rd[1], accB);
    accB = fmaf(n[3][0], rd[3], accB);
    return accA + accB;
}

__launch_bounds__(BLOCK, 4)   // VGPR<=128; single 160KB-LDS block, 16 waves/CU
__global__ void lagrange_kernel(const float* __restrict__ inputs,
                                const float* __restrict__ coe,
                                float* __restrict__ out,
                                int npts) {
    extern __shared__ _Float16 lds[];
    const int t = threadIdx.x;
    const int tid = blockIdx.x * BLOCK + t;
    const int stride = GRID * BLOCK;
    const float2* __restrict__ in2 = (const float2*)inputs;
    (void)npts;   // npts == GRID*BLOCK*16 exactly -> no bounds checks

    // ---- input prefetch issued before staging (R5; cold-HBM overlap) ----
    float2 a0 = in2[tid];
    float2 a1 = in2[tid + stride];
    float2 a2 = in2[tid + 2 * stride];
    float2 b0 = in2[tid + OUTER * stride];
    float2 b1 = in2[tid + (OUTER + 1) * stride];
    float2 b2 = in2[tid + (OUTER + 2) * stride];

    // ---- MAIN: 256 rows x 64 quads == 16 x 1024 tasks exactly, no tails ----
    // stored value = coe * s(row&3) * s(col&3), s = [1/24, -1/6, 1/4, -1/6]
#pragma unroll
    for (int k = 0; k < 16; ++k) {
        int g = t + k * BLOCK;
        int r = g >> 6;                 // 0..255
        int c4 = (g & 63) << 2;         // 0..252
        f4u q = *(const f4u*)(coe + r * NGRID + c4);
        float rs = rowscale(r);
        half4_t h = { (_Float16)(q.x * (rs * (1.0f / 24.0f))),
                      (_Float16)(q.y * (rs * (-1.0f / 6.0f))),
                      (_Float16)(q.z * (rs * 0.25f)),
                      (_Float16)(q.w * (rs * (-1.0f / 6.0f))) };
        *(half4_t*)(lds + (r << 8) + c4) = h;
    }
    // ---- S1: row 256 (rowscale 1/24), cols 0..255 ----
    if (t < 64) {
        int c4 = t << 2;
        f4u q = *(const f4u*)(coe + 256 * NGRID + c4);
        const float rs = 1.0f / 24.0f;
        half4_t h = { (_Float16)(q.x * (rs * (1.0f / 24.0f))),
                      (_Float16)(q.y * (rs * (-1.0f / 6.0f))),
                      (_Float16)(q.z * (rs * 0.25f)),
                      (_Float16)(q.w * (rs * (-1.0f / 6.0f))) };
        *(half4_t*)(lds + OFF1_H + c4) = h;
    }
    // ---- T: 8000 dwords == 7 x 1024 + 832 tasks. task = (d, c1):
    //      T[c1][d] = pack(coe[2d][4c1+4], coe[2d+1][4c1+4]) * scales ----
#pragma unroll
    for (int j = 0; j < 8; ++j) {
        int idx = t + j * BLOCK;
        if (idx < 8000) {
            int c1 = idx & 63;
            int d  = idx >> 6;          // 0..124
            const float* src = coe + (2 * d) * NGRID + 4 * c1 + 4;
            float va = src[0];
            float vb = src[NGRID];
            float rsa = (d & 1) ? 0.25f : (1.0f / 24.0f);   // rowscale(2d)
            va *= rsa * (1.0f / 24.0f);                     // colscale(col%4==0)
            vb *= (-1.0f / 6.0f) * (1.0f / 24.0f);          // rowscale(2d+1)
            ((unsigned*)lds)[T_DW + 125 * c1 + d] =
                __builtin_bit_cast(unsigned, pack2(va, vb));
        }
    }
    // ---- S2: col 256 (colscale 1/24), rows 248..256 ----
    if (t < 9) {
        int r = 248 + t;
        lds[S2_H + t] = (_Float16)(coe[r * NGRID + 256] * (rowscale(r) * (1.0f / 24.0f)));
    }
    __syncthreads();

    // Two point streams (k and k+OUTER), 3-deep input prefetch each.
#pragma unroll
    for (int k = 0; k < OUTER; ++k) {
        float2 a3, b3;
        if (k + 3 < OUTER) {
            a3 = in2[tid + (k + 3) * stride];
            b3 = in2[tid + (k + OUTER + 3) * stride];
        }
        float ra = eval_pt(lds, a0.x, a0.y);
        float rb = eval_pt(lds, b0.x, b0.y);
        __builtin_nontemporal_store(ra, &out[tid + k * stride]);
        __builtin_nontemporal_store(rb, &out[tid + (k + OUTER) * stride]);
        a0 = a1; a1 = a2; a2 = a3;
        b0 = b1; b1 = b2; b2 = b3;
    }
}

extern "C" void kernel_launch(void* const* d_in, const int* in_sizes, int n_in,
                              void* d_out, int out_size, void* d_ws, size_t ws_size,
                              hipStream_t stream) {
    const float* inputs = (const float*)d_in[0];   // (2048,2048,2) f32
    const float* coe    = (const float*)d_in[1];   // (257,257) f32
    float* out = (float*)d_out;                    // (2048,2048) f32
    int npts = out_size;                           // 4,194,304

    (void)hipFuncSetAttribute((const void*)lagrange_kernel,
                              hipFuncAttributeMaxDynamicSharedMemorySize,
                              LDS_BYTES);

    dim3 grid(GRID), block(BLOCK);   // 1 block/CU (LDS-limited), 16 waves/CU
    hipLaunchKernelGGL(lagrange_kernel, grid, block, LDS_BYTES, stream,
                       inputs, coe, out, npts);
}